// Round 1
// baseline (170.391 us; speedup 1.0000x reference)
//
#include <hip/hip_runtime.h>

#define BLOCK 256
#define GRID  1024

__device__ __forceinline__ float row_val(
    float x0, float x1, float x2, float x3,
    float u0, float u1, float m0, float m1, float sg,
    const float* q, float r0, float r1, float r2, float r3,
    float t0, float t1, float t2, float t3, float tr_c)
{
    // xr = X - x_target
    float xr0 = x0 - t0, xr1 = x1 - t1, xr2 = x2 - t2, xr3 = x3 - t3;
    // dyn = f X + G u + COV mu  (f,G,COV,omega hard-coded per reference)
    float dyn0 = x2 + 0.3f * u0;
    float dyn1 = x3 + 0.25f * u1;
    float dyn2 = 0.6f * x1 + u0 + 0.5f * m0;
    float dyn3 = -0.6f * x0 + u1 + 0.5f * m1;
    // qx_j = sum_i xr_i Q_ij   (general Q, row-major)
    float qx0 = xr0 * q[0] + xr1 * q[4] + xr2 * q[8]  + xr3 * q[12];
    float qx1 = xr0 * q[1] + xr1 * q[5] + xr2 * q[9]  + xr3 * q[13];
    float qx2 = xr0 * q[2] + xr1 * q[6] + xr2 * q[10] + xr3 * q[14];
    float qx3 = xr0 * q[3] + xr1 * q[7] + xr2 * q[11] + xr3 * q[15];
    float V    = qx0 * xr0 + qx1 * xr1 + qx2 * xr2 + qx3 * xr3;
    float g1   = 2.0f * (qx0 * dyn0 + qx1 * dyn1 + qx2 * dyn2 + qx3 * dyn3);
    float uRu  = 0.5f * (u0 * (r0 * u0 + r1 * u1) + u1 * (r2 * u0 + r3 * u1));
    float tt   = 0.5f * sg * sg * tr_c;
    return V + g1 + uRu + tt;
}

__global__ __launch_bounds__(BLOCK) void hjb_loss_kernel(
    const float* __restrict__ X,
    const float* __restrict__ mu,
    const float* __restrict__ sigma,
    const float* __restrict__ u,
    const float* __restrict__ Q,
    const float* __restrict__ R,
    const float* __restrict__ xt,
    float* __restrict__ out,
    int nquads, float inv_B)
{
    // Uniform-address loads of the small matrices -> scalar loads, broadcast.
    float q[16];
#pragma unroll
    for (int i = 0; i < 16; ++i) q[i] = Q[i];
    const float r0 = R[0], r1 = R[1], r2 = R[2], r3 = R[3];
    const float t0 = xt[0], t1 = xt[1], t2 = xt[2], t3 = xt[3];
    // trace(2Q @ COV COV^T): COV COV^T = diag(0,0,0.25,0.25)
    const float tr_c = 0.5f * (q[10] + q[15]);

    const float4* __restrict__ X4  = reinterpret_cast<const float4*>(X);
    const float4* __restrict__ u4  = reinterpret_cast<const float4*>(u);
    const float4* __restrict__ mu4 = reinterpret_cast<const float4*>(mu);
    const float4* __restrict__ s4  = reinterpret_cast<const float4*>(sigma);

    float acc = 0.0f;
    const int tid    = blockIdx.x * BLOCK + threadIdx.x;
    const int stride = gridDim.x * BLOCK;

    for (int qd = tid; qd < nquads; qd += stride) {
        // 4 rows per quad: all loads are 16B dwordx4
        float4 xa = X4[qd * 4 + 0];
        float4 xb = X4[qd * 4 + 1];
        float4 xc = X4[qd * 4 + 2];
        float4 xd = X4[qd * 4 + 3];
        float4 ua = u4[qd * 2 + 0];   // u rows 0,1
        float4 ub = u4[qd * 2 + 1];   // u rows 2,3
        float4 ma = mu4[qd * 2 + 0];
        float4 mb = mu4[qd * 2 + 1];
        float4 sg = s4[qd];

        acc += row_val(xa.x, xa.y, xa.z, xa.w, ua.x, ua.y, ma.x, ma.y, sg.x,
                       q, r0, r1, r2, r3, t0, t1, t2, t3, tr_c);
        acc += row_val(xb.x, xb.y, xb.z, xb.w, ua.z, ua.w, ma.z, ma.w, sg.y,
                       q, r0, r1, r2, r3, t0, t1, t2, t3, tr_c);
        acc += row_val(xc.x, xc.y, xc.z, xc.w, ub.x, ub.y, mb.x, mb.y, sg.z,
                       q, r0, r1, r2, r3, t0, t1, t2, t3, tr_c);
        acc += row_val(xd.x, xd.y, xd.z, xd.w, ub.z, ub.w, mb.z, mb.w, sg.w,
                       q, r0, r1, r2, r3, t0, t1, t2, t3, tr_c);
    }

    // scale early so final sum is O(1)
    acc *= inv_B;

    // 64-lane wave reduction
#pragma unroll
    for (int off = 32; off > 0; off >>= 1)
        acc += __shfl_down(acc, off, 64);

    __shared__ float wave_sums[BLOCK / 64];
    const int lane = threadIdx.x & 63;
    const int wid  = threadIdx.x >> 6;
    if (lane == 0) wave_sums[wid] = acc;
    __syncthreads();

    if (wid == 0) {
        float v = (lane < BLOCK / 64) ? wave_sums[lane] : 0.0f;
        v += __shfl_down(v, 2, 64);
        v += __shfl_down(v, 1, 64);
        if (lane == 0) atomicAdd(out, v);
    }
}

extern "C" void kernel_launch(void* const* d_in, const int* in_sizes, int n_in,
                              void* d_out, int out_size, void* d_ws, size_t ws_size,
                              hipStream_t stream) {
    const float* X     = (const float*)d_in[0];
    const float* mu    = (const float*)d_in[1];
    const float* sigma = (const float*)d_in[2];
    const float* u     = (const float*)d_in[3];
    const float* Q     = (const float*)d_in[4];
    const float* R     = (const float*)d_in[5];
    const float* xt    = (const float*)d_in[6];
    float* out = (float*)d_out;

    const int B = in_sizes[2];        // sigma is [B]
    const int nquads = B / 4;         // B = 4,194,304 -> divisible by 4
    const float inv_B = 1.0f / (float)B;

    hipMemsetAsync(out, 0, sizeof(float) * out_size, stream);
    hjb_loss_kernel<<<GRID, BLOCK, 0, stream>>>(
        X, mu, sigma, u, Q, R, xt, out, nquads, inv_B);
}